// Round 3
// baseline (901.301 us; speedup 1.0000x reference)
//
#include <hip/hip_runtime.h>
#include <hip/hip_fp16.h>

using f16   = _Float16;
using f16x8 = __attribute__((ext_vector_type(8))) f16;
using f32x4 = __attribute__((ext_vector_type(4))) float;

constexpr int S_LEN  = 2048;
constexpr int DMODEL = 1024;

static __device__ __forceinline__ f32x4 mfma16(f16x8 a, f16x8 b, f32x4 c) {
  return __builtin_amdgcn_mfma_f32_16x16x32_f16(a, b, c, 0, 0, 0);
}

// ---------------------------------------------------------------------------
// BT-GEMM: C[m,n] = sum_k A[m,k] * B[n,k]  (both K-major), K = DMODEL = 1024
// 128x128 tile, BK=32, 4 waves (2x2), each wave 64x64 = 4x4 MFMA frags.
// MODE 0: out f16 head-split [b,h,s,dk] (+bias)      (QKV projections)
// MODE 1: out f32 [m, n] = acc + bias + residual      (output projection)
// ---------------------------------------------------------------------------
template<bool A_F32, int MODE>
__device__ __forceinline__ void gemm_body(
    const void* __restrict__ Ap, const float* __restrict__ Bp,
    const float* __restrict__ bias, const float* __restrict__ res,
    void* __restrict__ Out)
{
  __shared__ f16 a_lds[128][40];   // 32 cols + 8 pad (80 B rows, 16B-aligned)
  __shared__ f16 b_lds[128][40];
  const int t    = threadIdx.x;
  const int lane = t & 63;
  const int w    = t >> 6;
  const int wm   = w >> 1, wn = w & 1;
  const int m0   = blockIdx.x * 128;
  const int n0   = blockIdx.y * 128;
  const int fr   = lane & 15, fg = lane >> 4;

  f32x4 acc[4][4];
#pragma unroll
  for (int i = 0; i < 4; ++i)
#pragma unroll
    for (int j = 0; j < 4; ++j) acc[i][j] = (f32x4){0.f, 0.f, 0.f, 0.f};

  const int sr = t >> 1;           // 0..127 staging row
  const int sc = (t & 1) * 16;     // 0 / 16

  for (int k0 = 0; k0 < DMODEL; k0 += 32) {
    __syncthreads();
    { // stage A tile (convert fp32 -> f16 if needed)
      alignas(16) f16 tmp[16];
      if constexpr (A_F32) {
        const float* src = (const float*)Ap + (size_t)(m0 + sr) * DMODEL + k0 + sc;
#pragma unroll
        for (int i = 0; i < 4; ++i) {
          const float4 f = *(const float4*)(src + i * 4);
          tmp[i*4+0] = (f16)f.x; tmp[i*4+1] = (f16)f.y;
          tmp[i*4+2] = (f16)f.z; tmp[i*4+3] = (f16)f.w;
        }
      } else {
        const f16* src = (const f16*)Ap + (size_t)(m0 + sr) * DMODEL + k0 + sc;
        *(f16x8*)&tmp[0] = *(const f16x8*)src;
        *(f16x8*)&tmp[8] = *(const f16x8*)(src + 8);
      }
      *(f16x8*)&a_lds[sr][sc]     = *(const f16x8*)&tmp[0];
      *(f16x8*)&a_lds[sr][sc + 8] = *(const f16x8*)&tmp[8];
    }
    { // stage B tile (weights, always fp32 [N][K])
      alignas(16) f16 tmp[16];
      const float* src = Bp + (size_t)(n0 + sr) * DMODEL + k0 + sc;
#pragma unroll
      for (int i = 0; i < 4; ++i) {
        const float4 f = *(const float4*)(src + i * 4);
        tmp[i*4+0] = (f16)f.x; tmp[i*4+1] = (f16)f.y;
        tmp[i*4+2] = (f16)f.z; tmp[i*4+3] = (f16)f.w;
      }
      *(f16x8*)&b_lds[sr][sc]     = *(const f16x8*)&tmp[0];
      *(f16x8*)&b_lds[sr][sc + 8] = *(const f16x8*)&tmp[8];
    }
    __syncthreads();
    f16x8 af[4], bf[4];
#pragma unroll
    for (int i = 0; i < 4; ++i)
      af[i] = *(const f16x8*)&a_lds[wm * 64 + i * 16 + fr][fg * 8];
#pragma unroll
    for (int i = 0; i < 4; ++i)
      bf[i] = *(const f16x8*)&b_lds[wn * 64 + i * 16 + fr][fg * 8];
#pragma unroll
    for (int mi = 0; mi < 4; ++mi)
#pragma unroll
      for (int ni = 0; ni < 4; ++ni)
        acc[mi][ni] = mfma16(af[mi], bf[ni], acc[mi][ni]);
  }

  // epilogue: C/D layout col = lane&15, row = (lane>>4)*4 + reg  [m89]
#pragma unroll
  for (int mi = 0; mi < 4; ++mi)
#pragma unroll
    for (int ni = 0; ni < 4; ++ni) {
      const int n  = n0 + wn * 64 + ni * 16 + fr;
      const float bv = bias[n];
#pragma unroll
      for (int r = 0; r < 4; ++r) {
        const int m = m0 + wm * 64 + mi * 16 + fg * 4 + r;
        const float v = acc[mi][ni][r] + bv;
        if constexpr (MODE == 0) {
          const int b = m >> 11, s = m & 2047, h = n >> 6, dk = n & 63;
          ((f16*)Out)[((size_t)(b * 16 + h) * S_LEN + s) * 64 + dk] = (f16)v;
        } else {
          const size_t idx = (size_t)m * DMODEL + n;
          ((float*)Out)[idx] = v + res[idx];
        }
      }
    }
}

struct QkvArgs {
  const float* A[3];
  const float* W[3];
  const float* bias[3];
  f16* out[3];
};

__global__ __launch_bounds__(256) void gemm_qkv_k(QkvArgs args) {
  const int z = blockIdx.z;
  gemm_body<true, 0>(args.A[z], args.W[z], args.bias[z], nullptr, args.out[z]);
}

__global__ __launch_bounds__(256) void gemm_proj_k(
    const f16* __restrict__ ctx, const float* __restrict__ Wo,
    const float* __restrict__ bo, const float* __restrict__ resid,
    float* __restrict__ proj) {
  gemm_body<false, 1>(ctx, Wo, bo, resid, proj);
}

// ---------------------------------------------------------------------------
// vh[bh][s][dk] -> vt[bh][dk][s]  (64x64 LDS tiles)
// ---------------------------------------------------------------------------
__global__ __launch_bounds__(256) void transpose_v_k(
    const f16* __restrict__ vh, f16* __restrict__ vt)
{
  __shared__ f16 tile[64][72];
  const int st = blockIdx.x;
  const int bh = blockIdx.y;
  const int t  = threadIdx.x;
  const int r  = t >> 2, c0 = (t & 3) * 16;
  const f16* src = vh + ((size_t)bh * S_LEN + st * 64 + r) * 64 + c0;
  *(f16x8*)&tile[r][c0]     = *(const f16x8*)src;
  *(f16x8*)&tile[r][c0 + 8] = *(const f16x8*)(src + 8);
  __syncthreads();
  alignas(16) f16 tmp[16];
#pragma unroll
  for (int j = 0; j < 16; ++j) tmp[j] = tile[c0 + j][r];
  f16* dst = vt + ((size_t)bh * 64 + r) * S_LEN + st * 64 + c0;
  *(f16x8*)dst       = *(f16x8*)&tmp[0];
  *(f16x8*)(dst + 8) = *(f16x8*)&tmp[8];
}

// ---------------------------------------------------------------------------
// Two-pass fused attention. Block = 64 q-rows x 4 waves (16 q-rows/wave).
// Pass1: online row max/sum over all K (QK^T recomputed, not stored).
// Pass2: recompute scores, p = exp(s-m)/l -> write fp32 attn (single HBM
//        write), p(f16) -> wave-private LDS -> PV MFMA accumulate.
// ---------------------------------------------------------------------------
__global__ __launch_bounds__(256) void attn_k(
    const f16* __restrict__ qh, const f16* __restrict__ kh,
    const f16* __restrict__ vt, float* __restrict__ attn,
    f16* __restrict__ ctx)
{
  __shared__ f16 q_lds[64][72];
  __shared__ f16 k_lds[64][72];
  __shared__ f16 v_lds[64][72];
  __shared__ f16 p_lds[64][72];

  const int t    = threadIdx.x;
  const int lane = t & 63;
  const int w    = t >> 6;
  const int fr   = lane & 15, fg = lane >> 4;
  const int bh   = blockIdx.y;
  const int q0   = blockIdx.x * 64;

  const int sr = t >> 2;
  const int sc = (t & 3) * 16;

  { // stage Q tile [64 q][64 dk]
    const f16* src = qh + ((size_t)bh * S_LEN + q0 + sr) * 64 + sc;
    *(f16x8*)&q_lds[sr][sc]     = *(const f16x8*)src;
    *(f16x8*)&q_lds[sr][sc + 8] = *(const f16x8*)(src + 8);
  }
  __syncthreads();
  const f16x8 aq0 = *(const f16x8*)&q_lds[w * 16 + fr][fg * 8];
  const f16x8 aq1 = *(const f16x8*)&q_lds[w * 16 + fr][32 + fg * 8];

  float m_run[4], l_run[4];
#pragma unroll
  for (int r = 0; r < 4; ++r) { m_run[r] = -1e30f; l_run[r] = 0.f; }

  const f16* kbase = kh + (size_t)bh * S_LEN * 64;
  const f16* vbase = vt + (size_t)bh * 64 * S_LEN;

  // ---- pass 1: row max / denom ----
  for (int kt = 0; kt < 32; ++kt) {
    __syncthreads();
    {
      const f16* src = kbase + (size_t)(kt * 64 + sr) * 64 + sc;
      *(f16x8*)&k_lds[sr][sc]     = *(const f16x8*)src;
      *(f16x8*)&k_lds[sr][sc + 8] = *(const f16x8*)(src + 8);
    }
    __syncthreads();
    float sv[4][4];
#pragma unroll
    for (int nb = 0; nb < 4; ++nb) {
      const f16x8 b0 = *(const f16x8*)&k_lds[nb * 16 + fr][fg * 8];
      const f16x8 b1 = *(const f16x8*)&k_lds[nb * 16 + fr][32 + fg * 8];
      f32x4 a = (f32x4){0.f, 0.f, 0.f, 0.f};
      a = mfma16(aq0, b0, a);
      a = mfma16(aq1, b1, a);
#pragma unroll
      for (int r = 0; r < 4; ++r) sv[nb][r] = a[r] * 0.125f;
    }
#pragma unroll
    for (int r = 0; r < 4; ++r) {
      float mx = fmaxf(fmaxf(sv[0][r], sv[1][r]), fmaxf(sv[2][r], sv[3][r]));
#pragma unroll
      for (int off = 8; off >= 1; off >>= 1) mx = fmaxf(mx, __shfl_xor(mx, off, 64));
      const float mnew = fmaxf(m_run[r], mx);
      float se = __expf(sv[0][r] - mnew) + __expf(sv[1][r] - mnew)
               + __expf(sv[2][r] - mnew) + __expf(sv[3][r] - mnew);
#pragma unroll
      for (int off = 8; off >= 1; off >>= 1) se += __shfl_xor(se, off, 64);
      l_run[r] = l_run[r] * __expf(m_run[r] - mnew) + se;
      m_run[r] = mnew;
    }
  }
  float inv_l[4];
#pragma unroll
  for (int r = 0; r < 4; ++r) inv_l[r] = 1.f / l_run[r];

  f32x4 cacc[4];
#pragma unroll
  for (int nb = 0; nb < 4; ++nb) cacc[nb] = (f32x4){0.f, 0.f, 0.f, 0.f};

  // ---- pass 2: write attn + PV ----
  for (int kt = 0; kt < 32; ++kt) {
    __syncthreads();
    {
      const f16* src = kbase + (size_t)(kt * 64 + sr) * 64 + sc;
      *(f16x8*)&k_lds[sr][sc]     = *(const f16x8*)src;
      *(f16x8*)&k_lds[sr][sc + 8] = *(const f16x8*)(src + 8);
      const f16* vsrc = vbase + (size_t)sr * S_LEN + kt * 64 + sc;
      *(f16x8*)&v_lds[sr][sc]     = *(const f16x8*)vsrc;
      *(f16x8*)&v_lds[sr][sc + 8] = *(const f16x8*)(vsrc + 8);
    }
    __syncthreads();
    float* arow = attn + ((size_t)bh * S_LEN + q0 + w * 16 + fg * 4) * S_LEN
                + (size_t)kt * 64 + fr;
#pragma unroll
    for (int nb = 0; nb < 4; ++nb) {
      const f16x8 b0 = *(const f16x8*)&k_lds[nb * 16 + fr][fg * 8];
      const f16x8 b1 = *(const f16x8*)&k_lds[nb * 16 + fr][32 + fg * 8];
      f32x4 a = (f32x4){0.f, 0.f, 0.f, 0.f};
      a = mfma16(aq0, b0, a);
      a = mfma16(aq1, b1, a);
#pragma unroll
      for (int r = 0; r < 4; ++r) {
        const float p = __expf(a[r] * 0.125f - m_run[r]) * inv_l[r];
        arow[(size_t)r * S_LEN + nb * 16] = p;                 // final attn value
        p_lds[w * 16 + fg * 4 + r][nb * 16 + fr] = (f16)p;     // wave-private rows
      }
    }
    // wave reads only its own 16 rows of p_lds -> no barrier needed
    const f16x8 ap0 = *(const f16x8*)&p_lds[w * 16 + fr][fg * 8];
    const f16x8 ap1 = *(const f16x8*)&p_lds[w * 16 + fr][32 + fg * 8];
#pragma unroll
    for (int nb = 0; nb < 4; ++nb) {
      const f16x8 b0 = *(const f16x8*)&v_lds[nb * 16 + fr][fg * 8];
      const f16x8 b1 = *(const f16x8*)&v_lds[nb * 16 + fr][32 + fg * 8];
      cacc[nb] = mfma16(ap0, b0, cacc[nb]);
      cacc[nb] = mfma16(ap1, b1, cacc[nb]);
    }
  }
  const int b = bh >> 4, h = bh & 15;
#pragma unroll
  for (int nb = 0; nb < 4; ++nb)
#pragma unroll
    for (int r = 0; r < 4; ++r) {
      const int srow = q0 + w * 16 + fg * 4 + r;
      ctx[(size_t)(b * S_LEN + srow) * DMODEL + h * 64 + nb * 16 + fr] =
          (f16)cacc[nb][r];
    }
}

// ---------------------------------------------------------------------------
// LayerNorm over last dim (1024), one block per row.
// ---------------------------------------------------------------------------
__global__ __launch_bounds__(256) void ln_k(
    const float* __restrict__ x, const float* __restrict__ gamma,
    const float* __restrict__ beta, float* __restrict__ out)
{
  const int row = blockIdx.x;
  const int t   = threadIdx.x;
  const float4 v = *(const float4*)(x + (size_t)row * DMODEL + t * 4);
  float s1 = v.x + v.y + v.z + v.w;
  float s2 = v.x * v.x + v.y * v.y + v.z * v.z + v.w * v.w;
#pragma unroll
  for (int off = 32; off >= 1; off >>= 1) {
    s1 += __shfl_xor(s1, off, 64);
    s2 += __shfl_xor(s2, off, 64);
  }
  __shared__ float r1[4], r2[4];
  if ((t & 63) == 0) { r1[t >> 6] = s1; r2[t >> 6] = s2; }
  __syncthreads();
  s1 = r1[0] + r1[1] + r1[2] + r1[3];
  s2 = r2[0] + r2[1] + r2[2] + r2[3];
  const float mu  = s1 * (1.f / 1024.f);
  const float var = s2 * (1.f / 1024.f) - mu * mu;
  const float rs  = rsqrtf(var + 1e-5f);
  const float4 g  = *(const float4*)(gamma + t * 4);
  const float4 be = *(const float4*)(beta + t * 4);
  float4 o;
  o.x = (v.x - mu) * rs * g.x + be.x;
  o.y = (v.y - mu) * rs * g.y + be.y;
  o.z = (v.z - mu) * rs * g.z + be.z;
  o.w = (v.w - mu) * rs * g.w + be.w;
  *(float4*)(out + (size_t)row * DMODEL + t * 4) = o;
}

// ---------------------------------------------------------------------------
extern "C" void kernel_launch(void* const* d_in, const int* in_sizes, int n_in,
                              void* d_out, int out_size, void* d_ws, size_t ws_size,
                              hipStream_t stream) {
  const float* query = (const float*)d_in[0];
  const float* key_  = (const float*)d_in[1];
  const float* value = (const float*)d_in[2];
  // d_in[3] = attn_mask: faithfully unused (reference discards masked_fill)
  const float* Wq = (const float*)d_in[4];
  const float* bq = (const float*)d_in[5];
  const float* Wk = (const float*)d_in[6];
  const float* bk = (const float*)d_in[7];
  const float* Wv = (const float*)d_in[8];
  const float* bv = (const float*)d_in[9];
  const float* Wo = (const float*)d_in[10];
  const float* bo = (const float*)d_in[11];
  const float* gamma = (const float*)d_in[12];
  const float* beta  = (const float*)d_in[13];

  float* out  = (float*)d_out;                 // [B,S,D] = 4,194,304 f32
  float* attn = out + 4194304;                 // [B,H,S,S] f32

  constexpr size_t NE = 4194304;               // elems of one [B,S,D] tensor
  f16* qh  = (f16*)d_ws;                       // [bh][s][dk] f16
  f16* kh  = qh + NE;
  f16* vh  = kh + NE;
  f16* vt  = vh + NE;                          // [bh][dk][s] f16
  f16* ctx = vt + NE;                          // [b,s,h,dk] f16
  float* proj = (float*)d_ws;                  // f32, aliases qh+kh (dead after attn)

  QkvArgs ga;
  ga.A[0] = query; ga.A[1] = key_; ga.A[2] = value;
  ga.W[0] = Wq;    ga.W[1] = Wk;   ga.W[2] = Wv;
  ga.bias[0] = bq; ga.bias[1] = bk; ga.bias[2] = bv;
  ga.out[0] = qh;  ga.out[1] = kh;  ga.out[2] = vh;

  gemm_qkv_k<<<dim3(32, 8, 3), 256, 0, stream>>>(ga);
  transpose_v_k<<<dim3(32, 32), 256, 0, stream>>>(vh, vt);
  attn_k<<<dim3(32, 32), 256, 0, stream>>>(qh, kh, vt, attn, ctx);
  gemm_proj_k<<<dim3(32, 8), 256, 0, stream>>>(ctx, Wo, bo, query, proj);
  ln_k<<<4096, 256, 0, stream>>>(proj, gamma, beta, out);
}